// Round 4
// baseline (321.578 us; speedup 1.0000x reference)
//
#include <hip/hip_runtime.h>

// RIIDModelLSTM: 2-layer LSTM (H=6) over T=512, B=8192, fused FC(6->32->1) head.
//
// Mapping (v4 = v3 + register pinning): 16 lanes per sequence, 2 waves/SIMD.
//   lane sub = tid&15; half = sub>>3; k = sub&7 (unit; k=6,7 padded, zero wts)
//   half=0 lane computes gates (i,f) of unit k; half=1 computes (g,o).
//   Gates packed as float2 (v_pk_fma_f32). One xor-8 swizzle swaps activations
//   so both halves hold (i,f,g,o) and redundantly compute c,h.
//   sigma/tanh unified: f(x) = 1 - B*rcp(1 + exp2(S*x)), S folded into weights.
//
// v4 key change: empty `asm volatile` pins on all loop-invariant weights.
// Evidence from R2/R3: VGPR_Count 56/88 (< ~115 live values needed) while the
// loop executed ~220 VALU inst/step vs ~90 in source -> the backend was
// rematerializing weight loads + scaling INSIDE the 512-step loop. An opaque
// asm result cannot be rematerialized, so RA must keep weights resident
// (budget = 256 VGPRs under waves_per_eu(2,2)).

typedef float v2f __attribute__((ext_vector_type(2)));

#define PIN(v) asm volatile("" : "+v"(v))

static constexpr float L2E = 1.44269504088896340736f;

template <int IMM>
__device__ __forceinline__ float swzf(float v) {
    return __int_as_float(__builtin_amdgcn_ds_swizzle(__float_as_int(v), IMM));
}

// broadcast lane ((lane&0x10)|J) of the 32-lane group -> unit J of own sequence
template <int J>
__device__ __forceinline__ float bcast16(float v) {
    return swzf<(J << 5) | 0x10>(v);
}

__device__ __forceinline__ float tanh_fast(float x) {
    float e = __builtin_amdgcn_exp2f((2.0f * L2E) * x);
    return 1.0f - 2.0f * __builtin_amdgcn_rcpf(1.0f + e);
}

extern "C" __global__ void __launch_bounds__(256)
__attribute__((amdgpu_waves_per_eu(2, 2)))
lstm_fused16(const float* __restrict__ x,
             const float* __restrict__ wih0, const float* __restrict__ whh0,
             const float* __restrict__ bih0, const float* __restrict__ bhh0,
             const float* __restrict__ wih1, const float* __restrict__ whh1,
             const float* __restrict__ bih1, const float* __restrict__ bhh1,
             const float* __restrict__ fc1w_g, const float* __restrict__ fc1b_g,
             const float* __restrict__ fc2w_g, const float* __restrict__ fc2b_g,
             float* __restrict__ out, int nbatch)
{
    const int tid  = blockIdx.x * blockDim.x + threadIdx.x;
    const int sub  = tid & 15;       // lane within sequence group
    const int seq  = tid >> 4;       // sequence index
    if (seq >= nbatch) return;

    const int   half = sub >> 3;     // 0: gates (i,f); 1: gates (g,o)
    const int   k    = sub & 7;      // hidden unit
    const float km   = (k < 6) ? 1.0f : 0.0f;   // pad lanes 6,7 -> zero weights
    const int   kk   = (k < 6) ? k : 0;

    // activation params: f(x)=1-B*rcp(1+exp2(S*x)); S folded into weights.
    // .x gate: sigmoid (half=0) or tanh (half=1); .y gate: always sigmoid.
    const float Bx  = half ? 2.0f : 1.0f;
    const float sxw = km * (half ? (2.0f * L2E) : L2E);
    const float syw = km * L2E;

    // ---- per-lane weights (gate rows 2*half, 2*half+1 of unit kk), pre-scaled
    const int r0 = (2 * half    ) * 6 + kk;
    const int r1 = (2 * half + 1) * 6 + kk;

    v2f wi0[6], wh0[6], wi1[6], wh1[6];
#pragma unroll
    for (int j = 0; j < 6; ++j) {
        wi0[j] = (v2f){ wih0[r0 * 6 + j] * sxw, wih0[r1 * 6 + j] * syw };
        wh0[j] = (v2f){ whh0[r0 * 6 + j] * sxw, whh0[r1 * 6 + j] * syw };
        wi1[j] = (v2f){ wih1[r0 * 6 + j] * sxw, wih1[r1 * 6 + j] * syw };
        wh1[j] = (v2f){ whh1[r0 * 6 + j] * sxw, whh1[r1 * 6 + j] * syw };
    }
    v2f bb0 = (v2f){ (bih0[r0] + bhh0[r0]) * sxw, (bih0[r1] + bhh0[r1]) * syw };
    v2f bb1 = (v2f){ (bih1[r0] + bhh1[r0]) * sxw, (bih1[r1] + bhh1[r1]) * syw };

    // ---- FC head: rows 2*sub, 2*sub+1 (all 32 rows covered by 16 lanes)
    v2f f1w[6];
    const int fr0 = 2 * sub, fr1 = 2 * sub + 1;
#pragma unroll
    for (int j = 0; j < 6; ++j)
        f1w[j] = (v2f){ fc1w_g[fr0 * 6 + j], fc1w_g[fr1 * 6 + j] };
    v2f   f1b = (v2f){ fc1b_g[fr0], fc1b_g[fr1] };
    v2f   f2w = (v2f){ fc2w_g[fr0], fc2w_g[fr1] };
    float f2b = fc2b_g[0];

    // ---- pin all loop-invariants: opaque to remat, must stay in VGPRs
#pragma unroll
    for (int j = 0; j < 6; ++j) {
        PIN(wi0[j]); PIN(wh0[j]); PIN(wi1[j]); PIN(wh1[j]); PIN(f1w[j]);
    }
    PIN(bb0); PIN(bb1); PIN(f1b); PIN(f2w); PIN(f2b);

    // ---- recurrent state
    float h0b[6], h1b[6];
#pragma unroll
    for (int j = 0; j < 6; ++j) { h0b[j] = 0.0f; h1b[j] = 0.0f; }
    float c0 = 0.0f, c1 = 0.0f;

    const float* xp = x + (size_t)seq * (512 * 6);
    float*       op = out + (size_t)seq * 512;

    // xc double-buffer: xcA holds x[t] for even t, xcB for odd t.
    float xcA[6], xcB[6];
    {
        float2 a = *(const float2*)(xp + 0);
        float2 b = *(const float2*)(xp + 2);
        float2 c = *(const float2*)(xp + 4);
        xcA[0] = a.x; xcA[1] = a.y; xcA[2] = b.x; xcA[3] = b.y; xcA[4] = c.x; xcA[5] = c.y;
    }

#define LSTM_STEP(T_, XC_, XN_, LAST_)                                          \
    {                                                                           \
        /* prefetch x[T_+1] into XN_ */                                         \
        if (!(LAST_)) {                                                         \
            const float* xnp = xp + ((T_) + 1) * 6;                             \
            float2 na = *(const float2*)(xnp + 0);                              \
            float2 nb = *(const float2*)(xnp + 2);                              \
            float2 nc = *(const float2*)(xnp + 4);                              \
            XN_[0] = na.x; XN_[1] = na.y; XN_[2] = nb.x;                        \
            XN_[3] = nb.y; XN_[4] = nc.x; XN_[5] = nc.y;                        \
        }                                                                       \
        /* deferred FC head on h1(t-1) */                                       \
        {                                                                       \
            v2f ra = f1b, rb = (v2f){0.0f, 0.0f};                               \
            ra += f1w[0] * h1b[0];  rb += f1w[1] * h1b[1];                      \
            ra += f1w[2] * h1b[2];  rb += f1w[3] * h1b[3];                      \
            ra += f1w[4] * h1b[4];  rb += f1w[5] * h1b[5];                      \
            v2f r = ra + rb;                                                    \
            float acc = f2w.x * fmaxf(r.x, 0.0f) + f2w.y * fmaxf(r.y, 0.0f);    \
            acc += swzf<0x041F>(acc);                                           \
            acc += swzf<0x081F>(acc);                                           \
            acc += swzf<0x101F>(acc);                                           \
            acc += swzf<0x201F>(acc);                                           \
            if ((T_) > 0 && sub == 0) op[(T_) - 1] = fmaxf(acc + f2b, 0.0f);    \
        }                                                                       \
        /* cell1 recurrent partial (h1(t-1) only): hoisted */                   \
        v2f a1a = bb1, a1b = (v2f){0.0f, 0.0f};                                 \
        a1a += wh1[0] * h1b[0];  a1b += wh1[1] * h1b[1];                        \
        a1a += wh1[2] * h1b[2];  a1b += wh1[3] * h1b[3];                        \
        a1a += wh1[4] * h1b[4];  a1b += wh1[5] * h1b[5];                        \
        /* cell 0 gates */                                                      \
        v2f ga = bb0, gb = (v2f){0.0f, 0.0f};                                   \
        ga += wi0[0] * XC_[0];   gb += wi0[1] * XC_[1];                         \
        ga += wi0[2] * XC_[2];   gb += wi0[3] * XC_[3];                         \
        ga += wi0[4] * XC_[4];   gb += wi0[5] * XC_[5];                         \
        ga += wh0[0] * h0b[0];   gb += wh0[1] * h0b[1];                         \
        ga += wh0[2] * h0b[2];   gb += wh0[3] * h0b[3];                         \
        ga += wh0[4] * h0b[4];   gb += wh0[5] * h0b[5];                         \
        v2f gv = ga + gb;                                                       \
        float ax = 1.0f - Bx * __builtin_amdgcn_rcpf(1.0f + __builtin_amdgcn_exp2f(gv.x)); \
        float ay = 1.0f -      __builtin_amdgcn_rcpf(1.0f + __builtin_amdgcn_exp2f(gv.y)); \
        float sx = swzf<0x201F>(ax);                                            \
        float sy = swzf<0x201F>(ay);                                            \
        float fg = half ? sy : ay;                                              \
        float og = half ? ay : sy;                                              \
        c0 = fg * c0 + ax * sx;                                                 \
        float h0 = og * tanh_fast(c0);                                          \
        h0b[0] = bcast16<0>(h0);                                                \
        h0b[1] = bcast16<1>(h0);                                                \
        h0b[2] = bcast16<2>(h0);                                                \
        h0b[3] = bcast16<3>(h0);                                                \
        h0b[4] = bcast16<4>(h0);                                                \
        h0b[5] = bcast16<5>(h0);                                                \
        /* cell 1 gates */                                                      \
        a1a += wi1[0] * h0b[0];  a1b += wi1[1] * h0b[1];                        \
        a1a += wi1[2] * h0b[2];  a1b += wi1[3] * h0b[3];                        \
        a1a += wi1[4] * h0b[4];  a1b += wi1[5] * h0b[5];                        \
        v2f g1 = a1a + a1b;                                                     \
        float ax1 = 1.0f - Bx * __builtin_amdgcn_rcpf(1.0f + __builtin_amdgcn_exp2f(g1.x)); \
        float ay1 = 1.0f -      __builtin_amdgcn_rcpf(1.0f + __builtin_amdgcn_exp2f(g1.y)); \
        float sx1 = swzf<0x201F>(ax1);                                          \
        float sy1 = swzf<0x201F>(ay1);                                          \
        float fg1 = half ? sy1 : ay1;                                           \
        float og1 = half ? ay1 : sy1;                                           \
        c1 = fg1 * c1 + ax1 * sx1;                                              \
        float h1 = og1 * tanh_fast(c1);                                         \
        h1b[0] = bcast16<0>(h1);                                                \
        h1b[1] = bcast16<1>(h1);                                                \
        h1b[2] = bcast16<2>(h1);                                                \
        h1b[3] = bcast16<3>(h1);                                                \
        h1b[4] = bcast16<4>(h1);                                                \
        h1b[5] = bcast16<5>(h1);                                                \
    }

    for (int t = 0; t < 512; t += 2) {
        LSTM_STEP(t,     xcA, xcB, false);
        LSTM_STEP(t + 1, xcB, xcA, (t + 1 == 511));
    }
#undef LSTM_STEP

    // ---- final FC head for t = 511
    {
        v2f ra = f1b, rb = (v2f){0.0f, 0.0f};
        ra += f1w[0] * h1b[0];  rb += f1w[1] * h1b[1];
        ra += f1w[2] * h1b[2];  rb += f1w[3] * h1b[3];
        ra += f1w[4] * h1b[4];  rb += f1w[5] * h1b[5];
        v2f r = ra + rb;
        float acc = f2w.x * fmaxf(r.x, 0.0f) + f2w.y * fmaxf(r.y, 0.0f);
        acc += swzf<0x041F>(acc);
        acc += swzf<0x081F>(acc);
        acc += swzf<0x101F>(acc);
        acc += swzf<0x201F>(acc);
        if (sub == 0) op[511] = fmaxf(acc + f2b, 0.0f);
    }
}

extern "C" void kernel_launch(void* const* d_in, const int* in_sizes, int n_in,
                              void* d_out, int out_size, void* d_ws, size_t ws_size,
                              hipStream_t stream) {
    const float* x     = (const float*)d_in[0];
    const float* wih0  = (const float*)d_in[1];
    const float* whh0  = (const float*)d_in[2];
    const float* bih0  = (const float*)d_in[3];
    const float* bhh0  = (const float*)d_in[4];
    const float* wih1  = (const float*)d_in[5];
    const float* whh1  = (const float*)d_in[6];
    const float* bih1  = (const float*)d_in[7];
    const float* bhh1  = (const float*)d_in[8];
    const float* fc1w  = (const float*)d_in[9];
    const float* fc1b  = (const float*)d_in[10];
    const float* fc2w  = (const float*)d_in[11];
    const float* fc2b  = (const float*)d_in[12];
    float* out = (float*)d_out;

    const int nbatch  = in_sizes[0] / (512 * 6);   // 8192
    const int threads = nbatch * 16;               // 16 lanes per sequence
    const int block   = 256;
    const int grid    = (threads + block - 1) / block;

    hipLaunchKernelGGL(lstm_fused16, dim3(grid), dim3(block), 0, stream,
                       x, wih0, whh0, bih0, bhh0, wih1, whh1, bih1, bhh1,
                       fc1w, fc1b, fc2w, fc2b, out, nbatch);
}

// Round 5
// 202.243 us; speedup vs baseline: 1.5901x; 1.5901x over previous
//
#include <hip/hip_runtime.h>

// RIIDModelLSTM: 2-layer LSTM (H=6), T=512, B=8192, fused FC(6->32->1) head.
//
// v5: ZERO-DS design. R1-R4 all plateaued at ~1750-1850 cyc/step because
// every step had 4-6 ds_swizzle round-trips (~120cyc each) on the critical
// path, and lgkmcnt's in-order semantics chained the "deferred" FC reduce's
// swizzles into the recurrent waits. This version does ALL cross-lane traffic
// with DPP (VALU pipe, ~2-4cyc):
//   - 8 lanes per sequence, mapped to an xor-closed coset of a 16-lane row:
//     coset = lanes {0-3,8-11} or {4-7,12-15}; position p = (l&3)|((l>>3)<<2).
//     xor-p-1 = quad_perm(1,0,3,2); xor-p-2 = quad_perm(2,3,0,1);
//     xor-p-4 = row_ror:8 (lane xor 8). All three are legal DPP ops.
//   - lane p owns hidden unit p (p=6,7 pad -> h stays exactly 0.0);
//     computes all 4 gates as two v2f pairs [i,f],[g,o]; activation scales
//     (-log2e / +2log2e) folded into the weights at load time.
//   - h all-gather = 7 dpp movs; gathered slot s holds unit (p^s), so
//     recurrent/fc weights are loaded PRE-PERMUTED per lane to match.
//   - FC head: rows 4p..4p+3 per lane (8 lanes = 32 rows), 3-dpp butterfly
//     reduce; out[t] buffered over 4 steps -> one dwordx4 store.
//   - x prefetched 4 steps deep (covers ~900cyc HBM latency at 1 wave/SIMD).
// Grid: 8192 seqs / 8 per wave = 1024 waves = 1 wave/SIMD (block=64).

typedef float v2f __attribute__((ext_vector_type(2)));

static constexpr float L2E  = 1.44269504088896340736f;
static constexpr float TL2E = 2.0f * L2E;

#define DPP_X1 0xB1   // quad_perm(1,0,3,2): lane xor 1
#define DPP_X2 0x4E   // quad_perm(2,3,0,1): lane xor 2
#define DPP_X8 0x128  // row_ror:8        : lane xor 8 (= p xor 4 in coset)

template<int CTRL>
__device__ __forceinline__ float dppf(float v) {
    return __int_as_float(__builtin_amdgcn_update_dpp(
        0, __float_as_int(v), CTRL, 0xF, 0xF, true));
}

#define PIN(v) asm volatile("" : "+v"(v))

// sigmoid with -log2e pre-folded:  a = -L2E*x  ->  1/(1+2^a)
__device__ __forceinline__ float sig_pre(float a) {
    return __builtin_amdgcn_rcpf(1.0f + __builtin_amdgcn_exp2f(a));
}
// tanh with +2log2e pre-folded:    a = 2*L2E*x ->  1 - 2/(1+2^a)
__device__ __forceinline__ float tanh_pre(float a) {
    return fmaf(-2.0f, __builtin_amdgcn_rcpf(1.0f + __builtin_amdgcn_exp2f(a)), 1.0f);
}

extern "C" __global__ void __launch_bounds__(64)
__attribute__((amdgpu_waves_per_eu(1, 1)))
lstm_dpp8(const float* __restrict__ x,
          const float* __restrict__ wih0, const float* __restrict__ whh0,
          const float* __restrict__ bih0, const float* __restrict__ bhh0,
          const float* __restrict__ wih1, const float* __restrict__ whh1,
          const float* __restrict__ bih1, const float* __restrict__ bhh1,
          const float* __restrict__ fc1w, const float* __restrict__ fc1b,
          const float* __restrict__ fc2w, const float* __restrict__ fc2b,
          float* __restrict__ out, int nbatch)
{
    const int L   = threadIdx.x;                 // 0..63
    const int l   = L & 15;
    const int row = L >> 4;                      // 0..3
    const int cst = (l >> 2) & 1;                // coset within row
    const int p   = (l & 3) | ((l >> 3) << 2);   // position in coset, 0..7

    int seq = blockIdx.x * 8 + row * 2 + cst;
    const bool live = (seq < nbatch);
    if (!live) seq = nbatch - 1;

    const float km = (p < 6) ? 1.0f : 0.0f;      // pad lanes 6,7
    const int   k  = (p < 6) ? p : 0;
    const int ir = k, fr = 6 + k, gr = 12 + k, orr = 18 + k;  // i,f,g,o rows

    // ---- weights: gate pairs A=[i,f] (both sigmoid, scale -L2E) and
    //               B=[g,o] (tanh +2L2E, sigmoid -L2E). x-part true order:
    v2f wiA0[6], wiB0[6];
#pragma unroll
    for (int j = 0; j < 6; ++j) {
        wiA0[j] = (v2f){ wih0[ir*6+j]*(-L2E)*km,  wih0[fr*6+j]*(-L2E)*km };
        wiB0[j] = (v2f){ wih0[gr*6+j]*( TL2E)*km, wih0[orr*6+j]*(-L2E)*km };
    }
    // h-parts and FC: PERMUTED layout, slot s multiplies h of unit (p^s)
    v2f whA0[8], whB0[8], wiA1[8], wiB1[8], whA1[8], whB1[8], f1wA[8], f1wB[8];
#pragma unroll
    for (int s = 0; s < 8; ++s) {
        const int   u  = p ^ s;
        const float cm = (u < 6) ? km   : 0.0f;   // gate weights: also pad-row zero
        const float fm = (u < 6) ? 1.0f : 0.0f;   // fc rows are real on ALL lanes
        const int   uc = (u < 6) ? u    : 0;
        whA0[s] = (v2f){ whh0[ir*6+uc]*(-L2E)*cm,  whh0[fr*6+uc]*(-L2E)*cm };
        whB0[s] = (v2f){ whh0[gr*6+uc]*( TL2E)*cm, whh0[orr*6+uc]*(-L2E)*cm };
        wiA1[s] = (v2f){ wih1[ir*6+uc]*(-L2E)*cm,  wih1[fr*6+uc]*(-L2E)*cm };
        wiB1[s] = (v2f){ wih1[gr*6+uc]*( TL2E)*cm, wih1[orr*6+uc]*(-L2E)*cm };
        whA1[s] = (v2f){ whh1[ir*6+uc]*(-L2E)*cm,  whh1[fr*6+uc]*(-L2E)*cm };
        whB1[s] = (v2f){ whh1[gr*6+uc]*( TL2E)*cm, whh1[orr*6+uc]*(-L2E)*cm };
        f1wA[s] = (v2f){ fc1w[(4*p+0)*6+uc]*fm, fc1w[(4*p+1)*6+uc]*fm };
        f1wB[s] = (v2f){ fc1w[(4*p+2)*6+uc]*fm, fc1w[(4*p+3)*6+uc]*fm };
    }
    v2f bbA0 = (v2f){ (bih0[ir]+bhh0[ir])*(-L2E)*km,  (bih0[fr]+bhh0[fr])*(-L2E)*km };
    v2f bbB0 = (v2f){ (bih0[gr]+bhh0[gr])*( TL2E)*km, (bih0[orr]+bhh0[orr])*(-L2E)*km };
    v2f bbA1 = (v2f){ (bih1[ir]+bhh1[ir])*(-L2E)*km,  (bih1[fr]+bhh1[fr])*(-L2E)*km };
    v2f bbB1 = (v2f){ (bih1[gr]+bhh1[gr])*( TL2E)*km, (bih1[orr]+bhh1[orr])*(-L2E)*km };
    v2f f1bA = (v2f){ fc1b[4*p+0], fc1b[4*p+1] };
    v2f f1bB = (v2f){ fc1b[4*p+2], fc1b[4*p+3] };
    v2f f2wA = (v2f){ fc2w[4*p+0], fc2w[4*p+1] };
    v2f f2wB = (v2f){ fc2w[4*p+2], fc2w[4*p+3] };
    float f2b = fc2b[0];

#pragma unroll
    for (int j = 0; j < 6; ++j) { PIN(wiA0[j]); PIN(wiB0[j]); }
#pragma unroll
    for (int s = 0; s < 8; ++s) {
        PIN(whA0[s]); PIN(whB0[s]); PIN(wiA1[s]); PIN(wiB1[s]);
        PIN(whA1[s]); PIN(whB1[s]); PIN(f1wA[s]); PIN(f1wB[s]);
    }
    PIN(bbA0); PIN(bbB0); PIN(bbA1); PIN(bbB1);
    PIN(f1bA); PIN(f1bB); PIN(f2wA); PIN(f2wB); PIN(f2b);

    // ---- state
    float h0s[8], h1s[8];
#pragma unroll
    for (int s = 0; s < 8; ++s) { h0s[s] = 0.0f; h1s[s] = 0.0f; }
    float c0 = 0.0f, c1 = 0.0f;

    const float* xp = x + (size_t)seq * (512 * 6);
    float*       op = out + (size_t)seq * 512;

    // ---- 4-deep x prefetch (float2 x3 per step)
    float2 xq[4][3];
#pragma unroll
    for (int j = 0; j < 4; ++j) {
        const float* q = xp + j * 6;
        xq[j][0] = *(const float2*)(q + 0);
        xq[j][1] = *(const float2*)(q + 2);
        xq[j][2] = *(const float2*)(q + 4);
    }

    const v2f Z2 = (v2f){0.0f, 0.0f};
    float y[4];

    for (int T = 0; T < 512; T += 4) {
        const int Tn = (T < 508) ? T + 4 : 508;   // clamped prefetch base
#pragma unroll
        for (int j = 0; j < 4; ++j) {
            // -- issue x[T+j+4] loads early (consumed next iteration)
            const float* xr = xp + (Tn + j) * 6;
            float2 nx0 = *(const float2*)(xr + 0);
            float2 nx1 = *(const float2*)(xr + 2);
            float2 nx2 = *(const float2*)(xr + 4);

            // -- cell1 recurrent partial (depends only on h1s): hoisted
            v2f pA = bbA1, pAb = Z2, pB = bbB1, pBb = Z2;
#pragma unroll
            for (int s = 0; s < 8; s += 2) {
                pA  += whA1[s]   * h1s[s];
                pAb += whA1[s+1] * h1s[s+1];
                pB  += whB1[s]   * h1s[s];
                pBb += whB1[s+1] * h1s[s+1];
            }

            // -- cell 0 gates
            v2f aA = bbA0, aAb = Z2, aB = bbB0, aBb = Z2;
            aA  += wiA0[0] * xq[j][0].x;  aAb += wiA0[1] * xq[j][0].y;
            aA  += wiA0[2] * xq[j][1].x;  aAb += wiA0[3] * xq[j][1].y;
            aA  += wiA0[4] * xq[j][2].x;  aAb += wiA0[5] * xq[j][2].y;
            aB  += wiB0[0] * xq[j][0].x;  aBb += wiB0[1] * xq[j][0].y;
            aB  += wiB0[2] * xq[j][1].x;  aBb += wiB0[3] * xq[j][1].y;
            aB  += wiB0[4] * xq[j][2].x;  aBb += wiB0[5] * xq[j][2].y;
#pragma unroll
            for (int s = 0; s < 8; s += 2) {
                aA  += whA0[s]   * h0s[s];
                aAb += whA0[s+1] * h0s[s+1];
                aB  += whB0[s]   * h0s[s];
                aBb += whB0[s+1] * h0s[s+1];
            }
            v2f gA0 = aA + aAb, gB0 = aB + aBb;
            float i0 = sig_pre(gA0.x), f0 = sig_pre(gA0.y);
            float g0 = tanh_pre(gB0.x), o0 = sig_pre(gB0.y);
            c0 = fmaf(f0, c0, i0 * g0);
            float h0 = o0 * tanh_pre(TL2E * c0);

            // -- h0 all-gather: 7 DPP movs, slot s = unit (p^s)
            h0s[0] = h0;
            h0s[1] = dppf<DPP_X1>(h0s[0]);
            h0s[2] = dppf<DPP_X2>(h0s[0]);
            h0s[3] = dppf<DPP_X2>(h0s[1]);
            h0s[4] = dppf<DPP_X8>(h0s[0]);
            h0s[5] = dppf<DPP_X8>(h0s[1]);
            h0s[6] = dppf<DPP_X8>(h0s[2]);
            h0s[7] = dppf<DPP_X8>(h0s[3]);

            // -- cell 1 finish (input part over h0 slots)
#pragma unroll
            for (int s = 0; s < 8; s += 2) {
                pA  += wiA1[s]   * h0s[s];
                pAb += wiA1[s+1] * h0s[s+1];
                pB  += wiB1[s]   * h0s[s];
                pBb += wiB1[s+1] * h0s[s+1];
            }
            v2f gA1 = pA + pAb, gB1 = pB + pBb;
            float i1 = sig_pre(gA1.x), f1 = sig_pre(gA1.y);
            float g1 = tanh_pre(gB1.x), o1 = sig_pre(gB1.y);
            c1 = fmaf(f1, c1, i1 * g1);
            float h1 = o1 * tanh_pre(TL2E * c1);

            // -- h1 all-gather
            h1s[0] = h1;
            h1s[1] = dppf<DPP_X1>(h1s[0]);
            h1s[2] = dppf<DPP_X2>(h1s[0]);
            h1s[3] = dppf<DPP_X2>(h1s[1]);
            h1s[4] = dppf<DPP_X8>(h1s[0]);
            h1s[5] = dppf<DPP_X8>(h1s[1]);
            h1s[6] = dppf<DPP_X8>(h1s[2]);
            h1s[7] = dppf<DPP_X8>(h1s[3]);

            // -- FC head on fresh h1 (off the recurrent dep-chain; scheduler
            //    overlaps it with the next step's cell0 automatically)
            v2f rA = f1bA, rAb = Z2, rB = f1bB, rBb = Z2;
#pragma unroll
            for (int s = 0; s < 8; s += 2) {
                rA  += f1wA[s]   * h1s[s];
                rAb += f1wA[s+1] * h1s[s+1];
                rB  += f1wB[s]   * h1s[s];
                rBb += f1wB[s+1] * h1s[s+1];
            }
            v2f RA = rA + rAb, RB = rB + rBb;
            RA.x = fmaxf(RA.x, 0.0f); RA.y = fmaxf(RA.y, 0.0f);
            RB.x = fmaxf(RB.x, 0.0f); RB.y = fmaxf(RB.y, 0.0f);
            float acc = RA.x * f2wA.x;
            acc = fmaf(RA.y, f2wA.y, acc);
            acc = fmaf(RB.x, f2wB.x, acc);
            acc = fmaf(RB.y, f2wB.y, acc);
            // butterfly reduce over the 8-lane coset (pure VALU)
            acc += dppf<DPP_X1>(acc);
            acc += dppf<DPP_X2>(acc);
            acc += dppf<DPP_X8>(acc);
            y[j] = fmaxf(acc + f2b, 0.0f);

            // -- rotate x prefetch
            xq[j][0] = nx0; xq[j][1] = nx1; xq[j][2] = nx2;
        }
        // -- one coalesced 16B out-store per 4 steps (lane p==0 of each coset)
        if (live && ((L & 11) == 0)) {
            float4 yv = make_float4(y[0], y[1], y[2], y[3]);
            *(float4*)(op + T) = yv;
        }
    }
}

extern "C" void kernel_launch(void* const* d_in, const int* in_sizes, int n_in,
                              void* d_out, int out_size, void* d_ws, size_t ws_size,
                              hipStream_t stream) {
    const float* x     = (const float*)d_in[0];
    const float* wih0  = (const float*)d_in[1];
    const float* whh0  = (const float*)d_in[2];
    const float* bih0  = (const float*)d_in[3];
    const float* bhh0  = (const float*)d_in[4];
    const float* wih1  = (const float*)d_in[5];
    const float* whh1  = (const float*)d_in[6];
    const float* bih1  = (const float*)d_in[7];
    const float* bhh1  = (const float*)d_in[8];
    const float* fc1w  = (const float*)d_in[9];
    const float* fc1b  = (const float*)d_in[10];
    const float* fc2w  = (const float*)d_in[11];
    const float* fc2b  = (const float*)d_in[12];
    float* out = (float*)d_out;

    const int nbatch = in_sizes[0] / (512 * 6);     // 8192
    const int grid   = (nbatch + 7) / 8;            // 8 seqs per 64-thread wave

    hipLaunchKernelGGL(lstm_dpp8, dim3(grid), dim3(64), 0, stream,
                       x, wih0, whh0, bih0, bhh0, wih1, whh1, bih1, bhh1,
                       fc1w, fc1b, fc2w, fc2b, out, nbatch);
}

// Round 6
// 198.999 us; speedup vs baseline: 1.6160x; 1.0163x over previous
//
#include <hip/hip_runtime.h>

// RIIDModelLSTM: 2-layer LSTM (H=6), T=512, B=8192, fused FC(6->32->1) head.
//
// v6 = v5 (zero-DS, DPP-only cross-lane, 8 lanes/seq) + two issue-count cuts:
//  1. FORCED packed math: inline-asm v_pk_fma_f32 / v_pk_add_f32. R5 counters
//     (748 busy-cyc/step vs ~420 expected packed) showed the backend
//     scalarized the ext_vector f32 ops. Broadcast operands use VOP3P
//     op_sel / op_sel_hi (h values packed pairwise; slot-pair = 2 pk_fma,
//     no broadcast movs).
//  2. UNIT-ORDERED gather: ror8 + 2 cndmask + 6 quad_perm broadcasts put
//     h[unit j] in slot j on every lane, so pad units 6,7 vanish from all
//     h-matrices uniformly (8 slots -> 6) and weights need no per-lane
//     permutation.
// Mapping unchanged: seq = 8-lane coset {quad, quad+8} of a 16-lane row;
// position p = (l&3)|((l>>3)<<2); lane p owns unit p (p=6,7 pad).
// Grid: 8192/8 = 1024 waves = 1 wave/SIMD, block=64.

typedef float v2f __attribute__((ext_vector_type(2)));

static constexpr float L2E  = 1.44269504088896340736f;
static constexpr float TL2E = 2.0f * L2E;

#define DPP_QP(a,b,c,d) ((a)|((b)<<2)|((c)<<4)|((d)<<6))
#define DPP_X1  DPP_QP(1,0,3,2)   // quad_perm xor-1
#define DPP_X2  DPP_QP(2,3,0,1)   // quad_perm xor-2
#define DPP_B0  DPP_QP(0,0,0,0)   // quad bcast lane0
#define DPP_B1  DPP_QP(1,1,1,1)
#define DPP_B2  DPP_QP(2,2,2,2)
#define DPP_B3  DPP_QP(3,3,3,3)
#define DPP_X8  0x128             // row_ror:8 = lane xor 8 inside 16-row

template<int CTRL>
__device__ __forceinline__ float dppf(float v) {
    return __int_as_float(__builtin_amdgcn_update_dpp(
        0, __float_as_int(v), CTRL, 0xF, 0xF, true));
}

#define PIN(v) asm volatile("" : "+v"(v))

// d += a * (b.lo, b.lo)   [VOP3P op_sel: src1 lo for both halves]
#define PKFMA_LO(d,a,b) asm("v_pk_fma_f32 %0, %1, %2, %0 op_sel:[0,0,0] op_sel_hi:[1,0,1]" : "+v"(d) : "v"(a), "v"(b))
// d += a * (b.hi, b.hi)
#define PKFMA_HI(d,a,b) asm("v_pk_fma_f32 %0, %1, %2, %0 op_sel:[0,1,0] op_sel_hi:[1,1,1]" : "+v"(d) : "v"(a), "v"(b))
#define PKADD(d,a,b)    asm("v_pk_add_f32 %0, %1, %2" : "=v"(d) : "v"(a), "v"(b))

// sigmoid, -log2e pre-folded:  a = -L2E*x  ->  1/(1+2^a)
__device__ __forceinline__ float sig_pre(float a) {
    return __builtin_amdgcn_rcpf(1.0f + __builtin_amdgcn_exp2f(a));
}
// tanh, +2log2e pre-folded:    a = 2*L2E*x ->  1 - 2/(1+2^a)
__device__ __forceinline__ float tanh_pre(float a) {
    return fmaf(-2.0f, __builtin_amdgcn_rcpf(1.0f + __builtin_amdgcn_exp2f(a)), 1.0f);
}

extern "C" __global__ void __launch_bounds__(64)
__attribute__((amdgpu_waves_per_eu(1, 1)))
lstm_dpp8v6(const float* __restrict__ x,
            const float* __restrict__ wih0, const float* __restrict__ whh0,
            const float* __restrict__ bih0, const float* __restrict__ bhh0,
            const float* __restrict__ wih1, const float* __restrict__ whh1,
            const float* __restrict__ bih1, const float* __restrict__ bhh1,
            const float* __restrict__ fc1w, const float* __restrict__ fc1b,
            const float* __restrict__ fc2w, const float* __restrict__ fc2b,
            float* __restrict__ out, int nbatch)
{
    const int L   = threadIdx.x;                 // 0..63
    const int l   = L & 15;
    const int row = L >> 4;                      // 0..3
    const int cst = (l >> 2) & 1;                // coset within row
    const int p   = (l & 3) | ((l >> 3) << 2);   // position in coset, 0..7
    const bool lowq = ((L >> 3) & 1) == 0;       // lane in units-0..3 quad

    int seq = blockIdx.x * 8 + row * 2 + cst;
    const bool live = (seq < nbatch);
    if (!live) seq = nbatch - 1;

    const float km = (p < 6) ? 1.0f : 0.0f;      // pad lanes 6,7 (h never read)
    const int   k  = (p < 6) ? p : 0;
    const int ir = k, fr = 6 + k, gr = 12 + k, orr = 18 + k;  // i,f,g,o rows

    // ---- weights. Gate pairs A=[i,f] (sigmoid,-L2E | sigmoid,-L2E),
    //               B=[g,o] (tanh,+2L2E | sigmoid,-L2E).
    // Slot j multiplies h[unit j] (unit-ordered; only 6 slots). No permutation.
    v2f wiA0[6], wiB0[6];                         // cell0 x-part, col j
    v2f whA0[6], whB0[6], wiA1[6], wiB1[6], whA1[6], whB1[6], f1wA[6], f1wB[6];
#pragma unroll
    for (int j = 0; j < 6; ++j) {
        wiA0[j] = (v2f){ wih0[ir*6+j]*(-L2E)*km,  wih0[fr*6+j]*(-L2E)*km };
        wiB0[j] = (v2f){ wih0[gr*6+j]*( TL2E)*km, wih0[orr*6+j]*(-L2E)*km };
        whA0[j] = (v2f){ whh0[ir*6+j]*(-L2E)*km,  whh0[fr*6+j]*(-L2E)*km };
        whB0[j] = (v2f){ whh0[gr*6+j]*( TL2E)*km, whh0[orr*6+j]*(-L2E)*km };
        wiA1[j] = (v2f){ wih1[ir*6+j]*(-L2E)*km,  wih1[fr*6+j]*(-L2E)*km };
        wiB1[j] = (v2f){ wih1[gr*6+j]*( TL2E)*km, wih1[orr*6+j]*(-L2E)*km };
        whA1[j] = (v2f){ whh1[ir*6+j]*(-L2E)*km,  whh1[fr*6+j]*(-L2E)*km };
        whB1[j] = (v2f){ whh1[gr*6+j]*( TL2E)*km, whh1[orr*6+j]*(-L2E)*km };
        f1wA[j] = (v2f){ fc1w[(4*p+0)*6+j], fc1w[(4*p+1)*6+j] };
        f1wB[j] = (v2f){ fc1w[(4*p+2)*6+j], fc1w[(4*p+3)*6+j] };
    }
    v2f bbA0 = (v2f){ (bih0[ir]+bhh0[ir])*(-L2E)*km,  (bih0[fr]+bhh0[fr])*(-L2E)*km };
    v2f bbB0 = (v2f){ (bih0[gr]+bhh0[gr])*( TL2E)*km, (bih0[orr]+bhh0[orr])*(-L2E)*km };
    v2f bbA1 = (v2f){ (bih1[ir]+bhh1[ir])*(-L2E)*km,  (bih1[fr]+bhh1[fr])*(-L2E)*km };
    v2f bbB1 = (v2f){ (bih1[gr]+bhh1[gr])*( TL2E)*km, (bih1[orr]+bhh1[orr])*(-L2E)*km };
    v2f f1bA = (v2f){ fc1b[4*p+0], fc1b[4*p+1] };
    v2f f1bB = (v2f){ fc1b[4*p+2], fc1b[4*p+3] };
    v2f f2wA = (v2f){ fc2w[4*p+0], fc2w[4*p+1] };
    v2f f2wB = (v2f){ fc2w[4*p+2], fc2w[4*p+3] };
    float f2b = fc2b[0];

#pragma unroll
    for (int j = 0; j < 6; ++j) {
        PIN(wiA0[j]); PIN(wiB0[j]); PIN(whA0[j]); PIN(whB0[j]);
        PIN(wiA1[j]); PIN(wiB1[j]); PIN(whA1[j]); PIN(whB1[j]);
        PIN(f1wA[j]); PIN(f1wB[j]);
    }
    PIN(bbA0); PIN(bbB0); PIN(bbA1); PIN(bbB1);
    PIN(f1bA); PIN(f1bB); PIN(f2wA); PIN(f2wB); PIN(f2b);

    // ---- state: h packed pairwise, units (0,1),(2,3),(4,5)
    v2f h0p[3], h1p[3];
    const v2f Z2 = (v2f){0.0f, 0.0f};
#pragma unroll
    for (int q = 0; q < 3; ++q) { h0p[q] = Z2; h1p[q] = Z2; }
    float c0 = 0.0f, c1 = 0.0f;

    const float* xp = x + (size_t)seq * (512 * 6);
    float*       op = out + (size_t)seq * 512;

    // ---- 4-deep x prefetch, pairs (x0,x1),(x2,x3),(x4,x5) as v2f
    v2f xq[4][3];
#pragma unroll
    for (int j = 0; j < 4; ++j) {
        const float* q = xp + j * 6;
        xq[j][0] = *(const v2f*)(q + 0);
        xq[j][1] = *(const v2f*)(q + 2);
        xq[j][2] = *(const v2f*)(q + 4);
    }

    // unit-ordered gather: h[unit j] -> slot j on every lane, 6 slots
#define GATHER(HP_, HV_)                                                        \
    {                                                                           \
        float u_ = dppf<DPP_X8>(HV_);            /* partner quad's h */         \
        float hl = lowq ? (HV_) : u_;            /* units 0-3 @ quad pos */     \
        float hh = lowq ? u_ : (HV_);            /* units 4-7 @ quad pos */     \
        HP_[0] = (v2f){ dppf<DPP_B0>(hl), dppf<DPP_B1>(hl) };                   \
        HP_[1] = (v2f){ dppf<DPP_B2>(hl), dppf<DPP_B3>(hl) };                   \
        HP_[2] = (v2f){ dppf<DPP_B0>(hh), dppf<DPP_B1>(hh) };                   \
    }

    float y[4];

    for (int T = 0; T < 512; T += 4) {
        const int Tn = (T < 508) ? T + 4 : 508;   // clamped prefetch base
#pragma unroll
        for (int j = 0; j < 4; ++j) {
            // -- issue x[T+j+4] loads early (consumed next outer iter)
            const float* xr = xp + (Tn + j) * 6;
            v2f nx0 = *(const v2f*)(xr + 0);
            v2f nx1 = *(const v2f*)(xr + 2);
            v2f nx2 = *(const v2f*)(xr + 4);

            // -- cell1 recurrent partial (depends only on h1p): hoisted
            v2f pA = bbA1, pA2 = Z2, pB = bbB1, pB2 = Z2;
            PKFMA_LO(pA, whA1[0], h1p[0]); PKFMA_HI(pA2, whA1[1], h1p[0]);
            PKFMA_LO(pA, whA1[2], h1p[1]); PKFMA_HI(pA2, whA1[3], h1p[1]);
            PKFMA_LO(pA, whA1[4], h1p[2]); PKFMA_HI(pA2, whA1[5], h1p[2]);
            PKFMA_LO(pB, whB1[0], h1p[0]); PKFMA_HI(pB2, whB1[1], h1p[0]);
            PKFMA_LO(pB, whB1[2], h1p[1]); PKFMA_HI(pB2, whB1[3], h1p[1]);
            PKFMA_LO(pB, whB1[4], h1p[2]); PKFMA_HI(pB2, whB1[5], h1p[2]);

            // -- cell 0 gates (x-part + h-part)
            v2f aA = bbA0, aA2 = Z2, aB = bbB0, aB2 = Z2;
            PKFMA_LO(aA, wiA0[0], xq[j][0]); PKFMA_HI(aA2, wiA0[1], xq[j][0]);
            PKFMA_LO(aA, wiA0[2], xq[j][1]); PKFMA_HI(aA2, wiA0[3], xq[j][1]);
            PKFMA_LO(aA, wiA0[4], xq[j][2]); PKFMA_HI(aA2, wiA0[5], xq[j][2]);
            PKFMA_LO(aB, wiB0[0], xq[j][0]); PKFMA_HI(aB2, wiB0[1], xq[j][0]);
            PKFMA_LO(aB, wiB0[2], xq[j][1]); PKFMA_HI(aB2, wiB0[3], xq[j][1]);
            PKFMA_LO(aB, wiB0[4], xq[j][2]); PKFMA_HI(aB2, wiB0[5], xq[j][2]);
            PKFMA_LO(aA, whA0[0], h0p[0]);  PKFMA_HI(aA2, whA0[1], h0p[0]);
            PKFMA_LO(aA, whA0[2], h0p[1]);  PKFMA_HI(aA2, whA0[3], h0p[1]);
            PKFMA_LO(aA, whA0[4], h0p[2]);  PKFMA_HI(aA2, whA0[5], h0p[2]);
            PKFMA_LO(aB, whB0[0], h0p[0]);  PKFMA_HI(aB2, whB0[1], h0p[0]);
            PKFMA_LO(aB, whB0[2], h0p[1]);  PKFMA_HI(aB2, whB0[3], h0p[1]);
            PKFMA_LO(aB, whB0[4], h0p[2]);  PKFMA_HI(aB2, whB0[5], h0p[2]);
            v2f gA0, gB0;
            PKADD(gA0, aA, aA2);
            PKADD(gB0, aB, aB2);

            float i0 = sig_pre(gA0.x), f0 = sig_pre(gA0.y);
            float g0 = tanh_pre(gB0.x), o0 = sig_pre(gB0.y);
            c0 = fmaf(f0, c0, i0 * g0);
            float h0 = o0 * tanh_pre(TL2E * c0);

            GATHER(h0p, h0);

            // -- cell 1 finish (input part over fresh h0)
            PKFMA_LO(pA, wiA1[0], h0p[0]); PKFMA_HI(pA2, wiA1[1], h0p[0]);
            PKFMA_LO(pA, wiA1[2], h0p[1]); PKFMA_HI(pA2, wiA1[3], h0p[1]);
            PKFMA_LO(pA, wiA1[4], h0p[2]); PKFMA_HI(pA2, wiA1[5], h0p[2]);
            PKFMA_LO(pB, wiB1[0], h0p[0]); PKFMA_HI(pB2, wiB1[1], h0p[0]);
            PKFMA_LO(pB, wiB1[2], h0p[1]); PKFMA_HI(pB2, wiB1[3], h0p[1]);
            PKFMA_LO(pB, wiB1[4], h0p[2]); PKFMA_HI(pB2, wiB1[5], h0p[2]);
            v2f gA1, gB1;
            PKADD(gA1, pA, pA2);
            PKADD(gB1, pB, pB2);

            float i1 = sig_pre(gA1.x), f1 = sig_pre(gA1.y);
            float g1 = tanh_pre(gB1.x), o1 = sig_pre(gB1.y);
            c1 = fmaf(f1, c1, i1 * g1);
            float h1 = o1 * tanh_pre(TL2E * c1);

            GATHER(h1p, h1);

            // -- FC head on fresh h1 (independent of next step's recurrence)
            v2f rA = f1bA, rA2 = Z2, rB = f1bB, rB2 = Z2;
            PKFMA_LO(rA, f1wA[0], h1p[0]); PKFMA_HI(rA2, f1wA[1], h1p[0]);
            PKFMA_LO(rA, f1wA[2], h1p[1]); PKFMA_HI(rA2, f1wA[3], h1p[1]);
            PKFMA_LO(rA, f1wA[4], h1p[2]); PKFMA_HI(rA2, f1wA[5], h1p[2]);
            PKFMA_LO(rB, f1wB[0], h1p[0]); PKFMA_HI(rB2, f1wB[1], h1p[0]);
            PKFMA_LO(rB, f1wB[2], h1p[1]); PKFMA_HI(rB2, f1wB[3], h1p[1]);
            PKFMA_LO(rB, f1wB[4], h1p[2]); PKFMA_HI(rB2, f1wB[5], h1p[2]);
            v2f RA, RB;
            PKADD(RA, rA, rA2);
            PKADD(RB, rB, rB2);
            float acc =          fmaxf(RA.x, 0.0f) * f2wA.x;
            acc = fmaf(fmaxf(RA.y, 0.0f), f2wA.y, acc);
            acc = fmaf(fmaxf(RB.x, 0.0f), f2wB.x, acc);
            acc = fmaf(fmaxf(RB.y, 0.0f), f2wB.y, acc);
            // butterfly reduce over the 8-lane coset (pure VALU)
            acc += dppf<DPP_X1>(acc);
            acc += dppf<DPP_X2>(acc);
            acc += dppf<DPP_X8>(acc);
            y[j] = fmaxf(acc + f2b, 0.0f);

            // -- rotate x prefetch
            xq[j][0] = nx0; xq[j][1] = nx1; xq[j][2] = nx2;
        }
        // -- one coalesced 16B out-store per 4 steps (lane p==0 of each coset)
        if (live && ((L & 11) == 0)) {
            float4 yv = make_float4(y[0], y[1], y[2], y[3]);
            *(float4*)(op + T) = yv;
        }
    }
}

extern "C" void kernel_launch(void* const* d_in, const int* in_sizes, int n_in,
                              void* d_out, int out_size, void* d_ws, size_t ws_size,
                              hipStream_t stream) {
    const float* x     = (const float*)d_in[0];
    const float* wih0  = (const float*)d_in[1];
    const float* whh0  = (const float*)d_in[2];
    const float* bih0  = (const float*)d_in[3];
    const float* bhh0  = (const float*)d_in[4];
    const float* wih1  = (const float*)d_in[5];
    const float* whh1  = (const float*)d_in[6];
    const float* bih1  = (const float*)d_in[7];
    const float* bhh1  = (const float*)d_in[8];
    const float* fc1w  = (const float*)d_in[9];
    const float* fc1b  = (const float*)d_in[10];
    const float* fc2w  = (const float*)d_in[11];
    const float* fc2b  = (const float*)d_in[12];
    float* out = (float*)d_out;

    const int nbatch = in_sizes[0] / (512 * 6);     // 8192
    const int grid   = (nbatch + 7) / 8;            // 8 seqs per 64-thread wave

    hipLaunchKernelGGL(lstm_dpp8v6, dim3(grid), dim3(64), 0, stream,
                       x, wih0, whh0, bih0, bhh0, wih1, whh1, bih1, bhh1,
                       fc1w, fc1b, fc2w, fc2b, out, nbatch);
}